// Round 6
// baseline (240.896 us; speedup 1.0000x reference)
//
#include <hip/hip_runtime.h>
#include <cstdint>
#include <cstddef>

#define B 128
#define P 8732
#define NC 21
#define O 16
#define THRESH 0.5f

typedef unsigned long long u64;
typedef unsigned int u32;

__device__ __forceinline__ float iou_pt(float a0, float a1, float a2, float a3,
                                        float b0, float b1, float b2, float b3) {
    float ltx = fmaxf(a0, b0), lty = fmaxf(a1, b1);
    float rbx = fminf(a2, b2), rby = fminf(a3, b3);
    float wx = fmaxf(rbx - ltx, 0.0f), wy = fmaxf(rby - lty, 0.0f);
    float inter = wx * wy;
    float aa = (a2 - a0) * (a3 - a1);
    float ab = (b2 - b0) * (b3 - b1);
    return inter / (aa + ab - inter);
}

// Pass 1: per-object best prior (argmax over p, first occurrence on tie).
__global__ void __launch_bounds__(256) k_pass1(const float* __restrict__ gt,
                                               const float* __restrict__ priors,
                                               u64* __restrict__ bestkey) {
    const int b = blockIdx.y;
    __shared__ float s_gt[O * 4];
    __shared__ u64 s_wk[4][O];
    const int tid = threadIdx.x;
    const int wave = tid >> 6, lane = tid & 63;
    if (tid < O * 4) {
        int o = tid >> 2, c = tid & 3;
        s_gt[tid] = gt[(b * O + o) * 5 + c];
    }
    __syncthreads();

    u64 lk[O];
#pragma unroll
    for (int o = 0; o < O; o++) lk[o] = 0ull;

    for (int p = blockIdx.x * 256 + tid; p < P; p += 2048) {
        float4 pr = reinterpret_cast<const float4*>(priors)[p];
        float b0 = pr.x - pr.z * 0.5f, b1 = pr.y - pr.w * 0.5f;
        float b2 = pr.x + pr.z * 0.5f, b3 = pr.y + pr.w * 0.5f;
#pragma unroll
        for (int o = 0; o < O; o++) {
            float v = iou_pt(s_gt[o * 4 + 0], s_gt[o * 4 + 1], s_gt[o * 4 + 2], s_gt[o * 4 + 3],
                             b0, b1, b2, b3);
            u64 key = ((u64)__float_as_uint(v) << 32) | (u64)(0xFFFFFFFFu - (u32)p);
            lk[o] = (key > lk[o]) ? key : lk[o];
        }
    }

#pragma unroll
    for (int o = 0; o < O; o++) {
        u64 k = lk[o];
#pragma unroll
        for (int off = 32; off > 0; off >>= 1) {
            u64 other = (u64)__shfl_xor((long long)k, off, 64);
            k = (other > k) ? other : k;
        }
        if (lane == 0) s_wk[wave][o] = k;
    }
    __syncthreads();
    if (tid < O) {
        u64 k = s_wk[0][tid];
#pragma unroll
        for (int w = 1; w < 4; w++) { u64 v = s_wk[w][tid]; k = (v > k) ? v : k; }
        atomicMax(&bestkey[b * O + tid], k);
    }
}

// Pass 2: wave-cooperative. Each wave stages 64 priors' scores (336 float4)
// via fully-coalesced loads into a PRIVATE LDS slab (no block barrier, only a
// wave-local lgkmcnt wait), then each lane computes one prior.
__global__ void __launch_bounds__(256) k_pass2(const float* __restrict__ gt,
                                               const float* __restrict__ priors,
                                               const u64* __restrict__ bestkey,
                                               const float* __restrict__ loc_preds,
                                               const float* __restrict__ scores,
                                               float* __restrict__ mine,
                                               int* __restrict__ num_pos,
                                               u32* __restrict__ total_pos,
                                               double* __restrict__ acc) {
    const int b = blockIdx.y;
    const int tid = threadIdx.x;
    const int wave = tid >> 6, lane = tid & 63;
    __shared__ float s_slab[4][1344];   // 64 priors * 21 floats per wave
    __shared__ float s_gt[O * 5];
    __shared__ int s_bp[O];

    if (tid < O * 5) s_gt[tid] = gt[b * O * 5 + tid];
    if (tid < O) s_bp[tid] = (int)(0xFFFFFFFFu - (u32)(bestkey[b * O + tid] & 0xFFFFFFFFull));
    __syncthreads();

    const int p0w = blockIdx.x * 256 + wave * 64;   // this wave's first prior
    const int nv = (P - p0w < 64) ? (P - p0w) : 64; // 64, 28, or <=0
    float l_loc = 0.f, l_ce = 0.f;
    int l_np = 0;

    if (nv > 0) {
        const int nf4 = nv * 21 / 4;   // 336 or 147
        const float4* src = reinterpret_cast<const float4*>(scores)
                            + ((size_t)b * P + (size_t)p0w) * NC / 4;
        float4* dst = reinterpret_cast<float4*>(&s_slab[wave][0]);
#pragma unroll
        for (int i = 0; i < 6; i++) {
            int idx = i * 64 + lane;
            if (idx < nf4) dst[idx] = src[idx];   // coalesced load + ds_write_b128
        }
        asm volatile("s_waitcnt lgkmcnt(0)" ::: "memory");
        __builtin_amdgcn_sched_barrier(0);

        if (lane < nv) {
            const int p = p0w + lane;
            float fs[NC];
#pragma unroll
            for (int c = 0; c < NC; c++) fs[c] = s_slab[wave][lane * NC + c];

            float4 pr = reinterpret_cast<const float4*>(priors)[p];
            float pb0 = pr.x - pr.z * 0.5f, pb1 = pr.y - pr.w * 0.5f;
            float pb2 = pr.x + pr.z * 0.5f, pb3 = pr.y + pr.w * 0.5f;

            float best_ov = -1.0f;
            int best_idx = 0;
#pragma unroll
            for (int o = 0; o < O; o++) {
                float v = iou_pt(s_gt[o * 5 + 0], s_gt[o * 5 + 1], s_gt[o * 5 + 2], s_gt[o * 5 + 3],
                                 pb0, pb1, pb2, pb3);
                if (v > best_ov) { best_ov = v; best_idx = o; }
            }
#pragma unroll
            for (int o = 0; o < O; o++) {
                if (s_bp[o] == p) { best_idx = o; best_ov = 2.0f; }   // last wins
            }
            int cls = (best_ov < THRESH) ? 0 : (int)s_gt[best_idx * 5 + 4];

            // tree max over 21
            float t[11];
#pragma unroll
            for (int i = 0; i < 10; i++) t[i] = fmaxf(fs[2 * i], fs[2 * i + 1]);
            t[10] = fs[20];
#pragma unroll
            for (int s = 11; s > 1; s = (s + 1) >> 1) {
#pragma unroll
                for (int i = 0; i < (s >> 1); i++) t[i] = fmaxf(t[i], t[s - 1 - i]);
            }
            float mx = t[0];

            float se0 = 0.f, se1 = 0.f, se2 = 0.f, se3 = 0.f;
#pragma unroll
            for (int c = 0; c < 20; c += 4) {
                se0 += __expf(fs[c + 0] - mx);
                se1 += __expf(fs[c + 1] - mx);
                se2 += __expf(fs[c + 2] - mx);
                se3 += __expf(fs[c + 3] - mx);
            }
            se0 += __expf(fs[20] - mx);
            float lse = mx + __logf((se0 + se1) + (se2 + se3));

            // gather fs[cls]: sum-of-selects (exactly one term nonzero)
            float g0 = 0.f, g1 = 0.f, g2 = 0.f, g3 = 0.f;
#pragma unroll
            for (int c = 0; c < 20; c += 4) {
                g0 += (c + 0 == cls) ? fs[c + 0] : 0.0f;
                g1 += (c + 1 == cls) ? fs[c + 1] : 0.0f;
                g2 += (c + 2 == cls) ? fs[c + 2] : 0.0f;
                g3 += (c + 3 == cls) ? fs[c + 3] : 0.0f;
            }
            g0 += (20 == cls) ? fs[20] : 0.0f;
            float ce = lse - ((g0 + g1) + (g2 + g3));

            bool pos = cls > 0;
            mine[(size_t)b * P + p] = pos ? 0.0f : ce;

            if (pos) {
                l_np = 1;
                l_ce = ce;
                float m0 = s_gt[best_idx * 5 + 0], m1 = s_gt[best_idx * 5 + 1];
                float m2 = s_gt[best_idx * 5 + 2], m3 = s_gt[best_idx * 5 + 3];
                float tx = ((m0 + m2) * 0.5f - pr.x) / (0.1f * pr.z);
                float ty = ((m1 + m3) * 0.5f - pr.y) / (0.1f * pr.w);
                float tw = __logf((m2 - m0) / pr.z) * 5.0f;
                float th = __logf((m3 - m1) / pr.w) * 5.0f;
                float4 lp = reinterpret_cast<const float4*>(loc_preds)[(size_t)b * P + p];
                float d0 = fabsf(lp.x - tx), d1 = fabsf(lp.y - ty);
                float d2 = fabsf(lp.z - tw), d3 = fabsf(lp.w - th);
                float s0 = d0 < 1.0f ? 0.5f * d0 * d0 : d0 - 0.5f;
                float s1 = d1 < 1.0f ? 0.5f * d1 * d1 : d1 - 0.5f;
                float s2 = d2 < 1.0f ? 0.5f * d2 * d2 : d2 - 0.5f;
                float s3 = d3 < 1.0f ? 0.5f * d3 * d3 : d3 - 0.5f;
                l_loc = (s0 + s1) + (s2 + s3);
            }
        }
    }

    // wave shuffle reductions (float partials -> double at wave leader)
#pragma unroll
    for (int off = 32; off > 0; off >>= 1) {
        l_loc += __shfl_xor(l_loc, off, 64);
        l_ce  += __shfl_xor(l_ce, off, 64);
        l_np  += __shfl_xor(l_np, off, 64);
    }
    __shared__ double s_loc[4], s_ce[4];
    __shared__ int s_np[4];
    if (lane == 0) { s_loc[wave] = (double)l_loc; s_ce[wave] = (double)l_ce; s_np[wave] = l_np; }
    __syncthreads();
    if (tid == 0) {
        double t_loc = (s_loc[0] + s_loc[1]) + (s_loc[2] + s_loc[3]);
        double t_ce  = (s_ce[0] + s_ce[1]) + (s_ce[2] + s_ce[3]);
        int t_np = s_np[0] + s_np[1] + s_np[2] + s_np[3];
        atomicAdd(&acc[0], t_loc);
        atomicAdd(&acc[1], t_ce);
        atomicAdd(&num_pos[b], t_np);
        atomicAdd(total_pos, (u32)t_np);
    }
}

// Top-k sum via radix select (wave-parallel bin scan) + fused finalize.
__global__ void __launch_bounds__(1024) k_hardneg(const float* __restrict__ mine,
                                                  const int* __restrict__ num_pos,
                                                  const u32* __restrict__ total_pos,
                                                  double* __restrict__ acc,
                                                  u32* __restrict__ ticket,
                                                  float* __restrict__ out) {
    const int b = blockIdx.x;
    const int tid = threadIdx.x;
    __shared__ float s_mine[P];
    __shared__ u32 s_hist[256];
    __shared__ u32 s_sel[2];
    __shared__ double s_red[16];

    const int tp = (int)*total_pos;
    const int np = num_pos[b];
    int k = 3 * np;
    int cap = P - tp - 1;
    if (cap < k) k = cap;

    if (k > 0) {
        for (int i = tid; i < P; i += 1024) s_mine[i] = mine[(size_t)b * P + i];
        if (tid == 0) { s_sel[0] = 0u; s_sel[1] = (u32)k; }
        __syncthreads();

        for (int shift = 24; shift >= 0; shift -= 8) {
            if (tid < 256) s_hist[tid] = 0u;
            __syncthreads();
            u32 prefix = s_sel[0];
            u32 kr = s_sel[1];
            u32 himask = (shift == 24) ? 0u : (0xFFFFFFFFu << (shift + 8));
            for (int i = tid; i < P; i += 1024) {
                u32 v = __float_as_uint(s_mine[i]);
                if ((v & himask) == prefix) atomicAdd(&s_hist[(v >> shift) & 255u], 1u);
            }
            __syncthreads();
            if (tid < 64) {
                const int L = tid;
                const int btop = 255 - 4 * L;
                u32 h0 = s_hist[btop], h1 = s_hist[btop - 1], h2 = s_hist[btop - 2], h3 = s_hist[btop - 3];
                u32 g4 = h0 + h1 + h2 + h3;
                u32 x = g4;
#pragma unroll
                for (int off = 1; off < 64; off <<= 1) {
                    u32 v = __shfl_up(x, off, 64);
                    if (L >= off) x += v;
                }
                u32 excl = x - g4;
                if (excl < kr && excl + g4 >= kr) {
                    u32 c = excl; int chosen = btop; u32 kloc = kr;
                    u32 nc;
                    nc = c + h0; if (c < kr && nc >= kr) { chosen = btop;     kloc = kr - c; } c = nc;
                    nc = c + h1; if (c < kr && nc >= kr) { chosen = btop - 1; kloc = kr - c; } c = nc;
                    nc = c + h2; if (c < kr && nc >= kr) { chosen = btop - 2; kloc = kr - c; } c = nc;
                    nc = c + h3; if (c < kr && nc >= kr) { chosen = btop - 3; kloc = kr - c; } c = nc;
                    s_sel[0] = prefix | ((u32)chosen << shift);
                    s_sel[1] = kloc;
                }
            }
            __syncthreads();
        }

        u32 tbits = s_sel[0];
        u32 kr = s_sel[1];
        float T = __uint_as_float(tbits);

        double sd = 0.0;
        for (int i = tid; i < P; i += 1024) {
            u32 v = __float_as_uint(s_mine[i]);
            if (v > tbits) sd += (double)s_mine[i];
        }
        const int lane = tid & 63;
        const int wave = tid >> 6;
#pragma unroll
        for (int off = 32; off > 0; off >>= 1) sd += __shfl_xor(sd, off, 64);
        if (lane == 0) s_red[wave] = sd;
        __syncthreads();
        if (tid == 0) {
            double tt = 0.0;
#pragma unroll
            for (int w = 0; w < 16; w++) tt += s_red[w];
            atomicAdd(&acc[2], tt + (double)kr * (double)T);
        }
    }

    __threadfence();
    __syncthreads();
    if (tid == 0) {
        u32 old = atomicAdd(ticket, 1u);
        if (old == B - 1) {
            __threadfence();
            double a0 = atomicAdd(&acc[0], 0.0);
            double a1 = atomicAdd(&acc[1], 0.0);
            double a2 = atomicAdd(&acc[2], 0.0);
            double n = (double)tp;
            out[0] = (float)(a0 / n);
            out[1] = (float)((a1 + a2) / n);
        }
    }
}

extern "C" void kernel_launch(void* const* d_in, const int* in_sizes, int n_in,
                              void* d_out, int out_size, void* d_ws, size_t ws_size,
                              hipStream_t stream) {
    const float* loc_preds = (const float*)d_in[0];
    const float* scores    = (const float*)d_in[1];
    const float* gt        = (const float*)d_in[2];
    const float* priors    = (const float*)d_in[3];

    char* ws = (char*)d_ws;
    double* acc    = (double*)ws;           // [0,24)
    u32* total_pos = (u32*)(ws + 24);       // [24,28)
    u32* ticket    = (u32*)(ws + 28);       // [28,32)
    int* num_pos   = (int*)(ws + 32);       // [32,544)
    u64* bestkey   = (u64*)(ws + 544);      // [544,16928)
    float* mine    = (float*)(ws + 16960);  // B*P*4 bytes

    hipMemsetAsync(d_ws, 0, 16960, stream);

    k_pass1<<<dim3(8, B), dim3(256), 0, stream>>>(gt, priors, bestkey);
    k_pass2<<<dim3((P + 255) / 256, B), dim3(256), 0, stream>>>(
        gt, priors, bestkey, loc_preds, scores, mine, num_pos, total_pos, acc);
    k_hardneg<<<dim3(B), dim3(1024), 0, stream>>>(mine, num_pos, total_pos, acc,
                                                  ticket, (float*)d_out);
}

// Round 7
// 239.203 us; speedup vs baseline: 1.0071x; 1.0071x over previous
//
#include <hip/hip_runtime.h>
#include <cstdint>
#include <cstddef>

#define B 128
#define P 8732
#define NC 21
#define O 16
#define THRESH 0.5f

typedef unsigned long long u64;
typedef unsigned int u32;

__device__ __forceinline__ float iou_pt(float a0, float a1, float a2, float a3,
                                        float b0, float b1, float b2, float b3) {
    float ltx = fmaxf(a0, b0), lty = fmaxf(a1, b1);
    float rbx = fminf(a2, b2), rby = fminf(a3, b3);
    float wx = fmaxf(rbx - ltx, 0.0f), wy = fmaxf(rby - lty, 0.0f);
    float inter = wx * wy;
    float aa = (a2 - a0) * (a3 - a1);
    float ab = (b2 - b0) * (b3 - b1);
    return inter / (aa + ab - inter);
}

// Pass 1: per-object best prior (argmax over p, first occurrence on tie).
__global__ void __launch_bounds__(256) k_pass1(const float* __restrict__ gt,
                                               const float* __restrict__ priors,
                                               u64* __restrict__ bestkey) {
    const int b = blockIdx.y;
    __shared__ float s_gt[O * 4];
    __shared__ u64 s_wk[4][O];
    const int tid = threadIdx.x;
    const int wave = tid >> 6, lane = tid & 63;
    if (tid < O * 4) {
        int o = tid >> 2, c = tid & 3;
        s_gt[tid] = gt[(b * O + o) * 5 + c];
    }
    __syncthreads();

    u64 lk[O];
#pragma unroll
    for (int o = 0; o < O; o++) lk[o] = 0ull;

    for (int p = blockIdx.x * 256 + tid; p < P; p += 2048) {
        float4 pr = reinterpret_cast<const float4*>(priors)[p];
        float b0 = pr.x - pr.z * 0.5f, b1 = pr.y - pr.w * 0.5f;
        float b2 = pr.x + pr.z * 0.5f, b3 = pr.y + pr.w * 0.5f;
#pragma unroll
        for (int o = 0; o < O; o++) {
            float v = iou_pt(s_gt[o * 4 + 0], s_gt[o * 4 + 1], s_gt[o * 4 + 2], s_gt[o * 4 + 3],
                             b0, b1, b2, b3);
            u64 key = ((u64)__float_as_uint(v) << 32) | (u64)(0xFFFFFFFFu - (u32)p);
            lk[o] = (key > lk[o]) ? key : lk[o];
        }
    }

#pragma unroll
    for (int o = 0; o < O; o++) {
        u64 k = lk[o];
#pragma unroll
        for (int off = 32; off > 0; off >>= 1) {
            u64 other = (u64)__shfl_xor((long long)k, off, 64);
            k = (other > k) ? other : k;
        }
        if (lane == 0) s_wk[wave][o] = k;
    }
    __syncthreads();
    if (tid < O) {
        u64 k = s_wk[0][tid];
#pragma unroll
        for (int w = 1; w < 4; w++) { u64 v = s_wk[w][tid]; k = (v > k) ? v : k; }
        atomicMax(&bestkey[b * O + tid], k);
    }
}

// Pass 2: wave-cooperative. Each wave DMA-stages 64 priors' scores into its
// private LDS slab via global_load_lds (no VGPR round-trip, fully coalesced,
// 6 outstanding), waits vmcnt(0) wave-locally (no block barrier), then each
// lane computes one prior from LDS (stride-21 reads: 2 lanes/bank = free).
__global__ void __launch_bounds__(256) k_pass2(const float* __restrict__ gt,
                                               const float* __restrict__ priors,
                                               const u64* __restrict__ bestkey,
                                               const float* __restrict__ loc_preds,
                                               const float* __restrict__ scores,
                                               float* __restrict__ mine,
                                               int* __restrict__ num_pos,
                                               u32* __restrict__ total_pos,
                                               double* __restrict__ acc) {
    const int b = blockIdx.y;
    const int tid = threadIdx.x;
    const int wave = tid >> 6, lane = tid & 63;
    __shared__ float s_slab[4][1344];   // 64 priors * 21 floats per wave
    __shared__ float s_gt[O * 5];
    __shared__ int s_bp[O];

    if (tid < O * 5) s_gt[tid] = gt[b * O * 5 + tid];
    if (tid < O) s_bp[tid] = (int)(0xFFFFFFFFu - (u32)(bestkey[b * O + tid] & 0xFFFFFFFFull));
    __syncthreads();

    const int p0w = blockIdx.x * 256 + wave * 64;   // this wave's first prior
    const int nv = (P - p0w < 64) ? (P - p0w) : 64; // 64, 28, or <=0
    float l_loc = 0.f, l_ce = 0.f;
    int l_np = 0;

    if (nv > 0) {
        const int nf4 = nv * 21 / 4;   // 336 or 147
        const char* src = (const char*)scores + ((size_t)b * P + (size_t)p0w) * NC * 4;
        char* slab = (char*)&s_slab[wave][0];
#pragma unroll
        for (int i = 0; i < 6; i++) {
            int idx = i * 64 + lane;
            if (idx < nf4) {
                __builtin_amdgcn_global_load_lds(
                    (const __attribute__((address_space(1))) u32*)(src + (size_t)idx * 16),
                    (__attribute__((address_space(3))) u32*)(slab + i * 1024),
                    16, 0, 0);
            }
        }
        asm volatile("s_waitcnt vmcnt(0)" ::: "memory");
        __builtin_amdgcn_sched_barrier(0);

        if (lane < nv) {
            const int p = p0w + lane;
            float fs[NC];
#pragma unroll
            for (int c = 0; c < NC; c++) fs[c] = s_slab[wave][lane * NC + c];

            float4 pr = reinterpret_cast<const float4*>(priors)[p];
            float pb0 = pr.x - pr.z * 0.5f, pb1 = pr.y - pr.w * 0.5f;
            float pb2 = pr.x + pr.z * 0.5f, pb3 = pr.y + pr.w * 0.5f;

            float best_ov = -1.0f;
            int best_idx = 0;
#pragma unroll
            for (int o = 0; o < O; o++) {
                float v = iou_pt(s_gt[o * 5 + 0], s_gt[o * 5 + 1], s_gt[o * 5 + 2], s_gt[o * 5 + 3],
                                 pb0, pb1, pb2, pb3);
                if (v > best_ov) { best_ov = v; best_idx = o; }
            }
#pragma unroll
            for (int o = 0; o < O; o++) {
                if (s_bp[o] == p) { best_idx = o; best_ov = 2.0f; }   // last wins
            }
            int cls = (best_ov < THRESH) ? 0 : (int)s_gt[best_idx * 5 + 4];

            // tree max over 21
            float t[11];
#pragma unroll
            for (int i = 0; i < 10; i++) t[i] = fmaxf(fs[2 * i], fs[2 * i + 1]);
            t[10] = fs[20];
#pragma unroll
            for (int s = 11; s > 1; s = (s + 1) >> 1) {
#pragma unroll
                for (int i = 0; i < (s >> 1); i++) t[i] = fmaxf(t[i], t[s - 1 - i]);
            }
            float mx = t[0];

            float se0 = 0.f, se1 = 0.f, se2 = 0.f, se3 = 0.f;
#pragma unroll
            for (int c = 0; c < 20; c += 4) {
                se0 += __expf(fs[c + 0] - mx);
                se1 += __expf(fs[c + 1] - mx);
                se2 += __expf(fs[c + 2] - mx);
                se3 += __expf(fs[c + 3] - mx);
            }
            se0 += __expf(fs[20] - mx);
            float lse = mx + __logf((se0 + se1) + (se2 + se3));

            // gather fs[cls]: sum-of-selects (exactly one term nonzero)
            float g0 = 0.f, g1 = 0.f, g2 = 0.f, g3 = 0.f;
#pragma unroll
            for (int c = 0; c < 20; c += 4) {
                g0 += (c + 0 == cls) ? fs[c + 0] : 0.0f;
                g1 += (c + 1 == cls) ? fs[c + 1] : 0.0f;
                g2 += (c + 2 == cls) ? fs[c + 2] : 0.0f;
                g3 += (c + 3 == cls) ? fs[c + 3] : 0.0f;
            }
            g0 += (20 == cls) ? fs[20] : 0.0f;
            float ce = lse - ((g0 + g1) + (g2 + g3));

            bool pos = cls > 0;
            mine[(size_t)b * P + p] = pos ? 0.0f : ce;

            if (pos) {
                l_np = 1;
                l_ce = ce;
                float m0 = s_gt[best_idx * 5 + 0], m1 = s_gt[best_idx * 5 + 1];
                float m2 = s_gt[best_idx * 5 + 2], m3 = s_gt[best_idx * 5 + 3];
                float tx = ((m0 + m2) * 0.5f - pr.x) / (0.1f * pr.z);
                float ty = ((m1 + m3) * 0.5f - pr.y) / (0.1f * pr.w);
                float tw = __logf((m2 - m0) / pr.z) * 5.0f;
                float th = __logf((m3 - m1) / pr.w) * 5.0f;
                float4 lp = reinterpret_cast<const float4*>(loc_preds)[(size_t)b * P + p];
                float d0 = fabsf(lp.x - tx), d1 = fabsf(lp.y - ty);
                float d2 = fabsf(lp.z - tw), d3 = fabsf(lp.w - th);
                float s0 = d0 < 1.0f ? 0.5f * d0 * d0 : d0 - 0.5f;
                float s1 = d1 < 1.0f ? 0.5f * d1 * d1 : d1 - 0.5f;
                float s2 = d2 < 1.0f ? 0.5f * d2 * d2 : d2 - 0.5f;
                float s3 = d3 < 1.0f ? 0.5f * d3 * d3 : d3 - 0.5f;
                l_loc = (s0 + s1) + (s2 + s3);
            }
        }
    }

    // wave shuffle reductions (float partials -> double at wave leader)
#pragma unroll
    for (int off = 32; off > 0; off >>= 1) {
        l_loc += __shfl_xor(l_loc, off, 64);
        l_ce  += __shfl_xor(l_ce, off, 64);
        l_np  += __shfl_xor(l_np, off, 64);
    }
    __shared__ double s_loc[4], s_ce[4];
    __shared__ int s_np[4];
    if (lane == 0) { s_loc[wave] = (double)l_loc; s_ce[wave] = (double)l_ce; s_np[wave] = l_np; }
    __syncthreads();
    if (tid == 0) {
        double t_loc = (s_loc[0] + s_loc[1]) + (s_loc[2] + s_loc[3]);
        double t_ce  = (s_ce[0] + s_ce[1]) + (s_ce[2] + s_ce[3]);
        int t_np = s_np[0] + s_np[1] + s_np[2] + s_np[3];
        atomicAdd(&acc[0], t_loc);
        atomicAdd(&acc[1], t_ce);
        atomicAdd(&num_pos[b], t_np);
        atomicAdd(total_pos, (u32)t_np);
    }
}

// Top-k sum via radix select (wave-parallel bin scan) + fused finalize.
__global__ void __launch_bounds__(1024) k_hardneg(const float* __restrict__ mine,
                                                  const int* __restrict__ num_pos,
                                                  const u32* __restrict__ total_pos,
                                                  double* __restrict__ acc,
                                                  u32* __restrict__ ticket,
                                                  float* __restrict__ out) {
    const int b = blockIdx.x;
    const int tid = threadIdx.x;
    __shared__ float s_mine[P];
    __shared__ u32 s_hist[256];
    __shared__ u32 s_sel[2];
    __shared__ double s_red[16];

    const int tp = (int)*total_pos;
    const int np = num_pos[b];
    int k = 3 * np;
    int cap = P - tp - 1;
    if (cap < k) k = cap;

    if (k > 0) {
        for (int i = tid; i < P; i += 1024) s_mine[i] = mine[(size_t)b * P + i];
        if (tid == 0) { s_sel[0] = 0u; s_sel[1] = (u32)k; }
        __syncthreads();

        for (int shift = 24; shift >= 0; shift -= 8) {
            if (tid < 256) s_hist[tid] = 0u;
            __syncthreads();
            u32 prefix = s_sel[0];
            u32 kr = s_sel[1];
            u32 himask = (shift == 24) ? 0u : (0xFFFFFFFFu << (shift + 8));
            for (int i = tid; i < P; i += 1024) {
                u32 v = __float_as_uint(s_mine[i]);
                if ((v & himask) == prefix) atomicAdd(&s_hist[(v >> shift) & 255u], 1u);
            }
            __syncthreads();
            if (tid < 64) {
                const int L = tid;
                const int btop = 255 - 4 * L;
                u32 h0 = s_hist[btop], h1 = s_hist[btop - 1], h2 = s_hist[btop - 2], h3 = s_hist[btop - 3];
                u32 g4 = h0 + h1 + h2 + h3;
                u32 x = g4;
#pragma unroll
                for (int off = 1; off < 64; off <<= 1) {
                    u32 v = __shfl_up(x, off, 64);
                    if (L >= off) x += v;
                }
                u32 excl = x - g4;
                if (excl < kr && excl + g4 >= kr) {
                    u32 c = excl; int chosen = btop; u32 kloc = kr;
                    u32 nc;
                    nc = c + h0; if (c < kr && nc >= kr) { chosen = btop;     kloc = kr - c; } c = nc;
                    nc = c + h1; if (c < kr && nc >= kr) { chosen = btop - 1; kloc = kr - c; } c = nc;
                    nc = c + h2; if (c < kr && nc >= kr) { chosen = btop - 2; kloc = kr - c; } c = nc;
                    nc = c + h3; if (c < kr && nc >= kr) { chosen = btop - 3; kloc = kr - c; } c = nc;
                    s_sel[0] = prefix | ((u32)chosen << shift);
                    s_sel[1] = kloc;
                }
            }
            __syncthreads();
        }

        u32 tbits = s_sel[0];
        u32 kr = s_sel[1];
        float T = __uint_as_float(tbits);

        double sd = 0.0;
        for (int i = tid; i < P; i += 1024) {
            u32 v = __float_as_uint(s_mine[i]);
            if (v > tbits) sd += (double)s_mine[i];
        }
        const int lane = tid & 63;
        const int wave = tid >> 6;
#pragma unroll
        for (int off = 32; off > 0; off >>= 1) sd += __shfl_xor(sd, off, 64);
        if (lane == 0) s_red[wave] = sd;
        __syncthreads();
        if (tid == 0) {
            double tt = 0.0;
#pragma unroll
            for (int w = 0; w < 16; w++) tt += s_red[w];
            atomicAdd(&acc[2], tt + (double)kr * (double)T);
        }
    }

    __threadfence();
    __syncthreads();
    if (tid == 0) {
        u32 old = atomicAdd(ticket, 1u);
        if (old == B - 1) {
            __threadfence();
            double a0 = atomicAdd(&acc[0], 0.0);
            double a1 = atomicAdd(&acc[1], 0.0);
            double a2 = atomicAdd(&acc[2], 0.0);
            double n = (double)tp;
            out[0] = (float)(a0 / n);
            out[1] = (float)((a1 + a2) / n);
        }
    }
}

extern "C" void kernel_launch(void* const* d_in, const int* in_sizes, int n_in,
                              void* d_out, int out_size, void* d_ws, size_t ws_size,
                              hipStream_t stream) {
    const float* loc_preds = (const float*)d_in[0];
    const float* scores    = (const float*)d_in[1];
    const float* gt        = (const float*)d_in[2];
    const float* priors    = (const float*)d_in[3];

    char* ws = (char*)d_ws;
    double* acc    = (double*)ws;           // [0,24)
    u32* total_pos = (u32*)(ws + 24);       // [24,28)
    u32* ticket    = (u32*)(ws + 28);       // [28,32)
    int* num_pos   = (int*)(ws + 32);       // [32,544)
    u64* bestkey   = (u64*)(ws + 544);      // [544,16928)
    float* mine    = (float*)(ws + 16960);  // B*P*4 bytes

    hipMemsetAsync(d_ws, 0, 16960, stream);

    k_pass1<<<dim3(8, B), dim3(256), 0, stream>>>(gt, priors, bestkey);
    k_pass2<<<dim3((P + 255) / 256, B), dim3(256), 0, stream>>>(
        gt, priors, bestkey, loc_preds, scores, mine, num_pos, total_pos, acc);
    k_hardneg<<<dim3(B), dim3(1024), 0, stream>>>(mine, num_pos, total_pos, acc,
                                                  ticket, (float*)d_out);
}

// Round 8
// 105.658 us; speedup vs baseline: 2.2800x; 2.2639x over previous
//
#include <hip/hip_runtime.h>
#include <cstdint>
#include <cstddef>

#define B 128
#define P 8732
#define NC 21
#define O 16
#define THRESH 0.5f
#define QPI 2183   // quads per image = P/4
#define NBX 9      // pass2 blocks per image
#define NPART (B * NBX)

typedef unsigned long long u64;
typedef unsigned int u32;

__device__ __forceinline__ float iou_pt(float a0, float a1, float a2, float a3,
                                        float b0, float b1, float b2, float b3) {
    float ltx = fmaxf(a0, b0), lty = fmaxf(a1, b1);
    float rbx = fminf(a2, b2), rby = fminf(a3, b3);
    float wx = fmaxf(rbx - ltx, 0.0f), wy = fmaxf(rby - lty, 0.0f);
    float inter = wx * wy;
    float aa = (a2 - a0) * (a3 - a1);
    float ab = (b2 - b0) * (b3 - b1);
    return inter / (aa + ab - inter);
}

// Pass 1: per-object best prior (argmax over p, first occurrence on tie).
__global__ void __launch_bounds__(256) k_pass1(const float* __restrict__ gt,
                                               const float* __restrict__ priors,
                                               u64* __restrict__ bestkey) {
    const int b = blockIdx.y;
    __shared__ float s_gt[O * 4];
    __shared__ u64 s_wk[4][O];
    const int tid = threadIdx.x;
    const int wave = tid >> 6, lane = tid & 63;
    if (tid < O * 4) {
        int o = tid >> 2, c = tid & 3;
        s_gt[tid] = gt[(b * O + o) * 5 + c];
    }
    __syncthreads();

    u64 lk[O];
#pragma unroll
    for (int o = 0; o < O; o++) lk[o] = 0ull;

    for (int p = blockIdx.x * 256 + tid; p < P; p += 2048) {
        float4 pr = reinterpret_cast<const float4*>(priors)[p];
        float b0 = pr.x - pr.z * 0.5f, b1 = pr.y - pr.w * 0.5f;
        float b2 = pr.x + pr.z * 0.5f, b3 = pr.y + pr.w * 0.5f;
#pragma unroll
        for (int o = 0; o < O; o++) {
            float v = iou_pt(s_gt[o * 4 + 0], s_gt[o * 4 + 1], s_gt[o * 4 + 2], s_gt[o * 4 + 3],
                             b0, b1, b2, b3);
            u64 key = ((u64)__float_as_uint(v) << 32) | (u64)(0xFFFFFFFFu - (u32)p);
            lk[o] = (key > lk[o]) ? key : lk[o];
        }
    }

#pragma unroll
    for (int o = 0; o < O; o++) {
        u64 k = lk[o];
#pragma unroll
        for (int off = 32; off > 0; off >>= 1) {
            u64 other = (u64)__shfl_xor((long long)k, off, 64);
            k = (other > k) ? other : k;
        }
        if (lane == 0) s_wk[wave][o] = k;
    }
    __syncthreads();
    if (tid < O) {
        u64 k = s_wk[0][tid];
#pragma unroll
        for (int w = 1; w < 4; w++) { u64 v = s_wk[w][tid]; k = (v > k) ? v : k; }
        atomicMax(&bestkey[b * O + tid], k);
    }
}

// Pass 2: R4 structure (4 priors/thread, 21 independent float4 register
// loads), but NO global atomics: per-block partials to workspace.
__global__ void __launch_bounds__(256) k_pass2(const float* __restrict__ gt,
                                               const float* __restrict__ priors,
                                               const u64* __restrict__ bestkey,
                                               const float* __restrict__ loc_preds,
                                               const float* __restrict__ scores,
                                               float* __restrict__ mine,
                                               double* __restrict__ pl,
                                               double* __restrict__ pc,
                                               int* __restrict__ pn) {
    const int b = blockIdx.y;
    __shared__ float s_gt[O * 5];
    __shared__ int s_bp[O];
    const int tid = threadIdx.x;
    if (tid < O * 5) s_gt[tid] = gt[b * O * 5 + tid];
    if (tid < O) s_bp[tid] = (int)(0xFFFFFFFFu - (u32)(bestkey[b * O + tid] & 0xFFFFFFFFull));
    __syncthreads();

    const int gq = blockIdx.x * 256 + tid;  // quad index within image
    double l_loc = 0.0, l_ce = 0.0;
    int l_np = 0;

    if (gq < QPI) {
        const int p0 = gq * 4;
        float fs[84];
        const float4* s4 = reinterpret_cast<const float4*>(scores)
                           + (size_t)b * (size_t)(P * NC / 4) + (size_t)21 * gq;
#pragma unroll
        for (int i = 0; i < 21; i++) {
            float4 v = s4[i];
            fs[4 * i + 0] = v.x; fs[4 * i + 1] = v.y;
            fs[4 * i + 2] = v.z; fs[4 * i + 3] = v.w;
        }
        float4 pr4[4];
#pragma unroll
        for (int j = 0; j < 4; j++) pr4[j] = reinterpret_cast<const float4*>(priors)[p0 + j];

        float mine_v[4];

#pragma unroll
        for (int j = 0; j < 4; j++) {
            const int p = p0 + j;
            const float4 pr = pr4[j];
            float pb0 = pr.x - pr.z * 0.5f, pb1 = pr.y - pr.w * 0.5f;
            float pb2 = pr.x + pr.z * 0.5f, pb3 = pr.y + pr.w * 0.5f;

            float best_ov = -1.0f;
            int best_idx = 0;
#pragma unroll
            for (int o = 0; o < O; o++) {
                float v = iou_pt(s_gt[o * 5 + 0], s_gt[o * 5 + 1], s_gt[o * 5 + 2], s_gt[o * 5 + 3],
                                 pb0, pb1, pb2, pb3);
                if (v > best_ov) { best_ov = v; best_idx = o; }
            }
#pragma unroll
            for (int o = 0; o < O; o++) {
                if (s_bp[o] == p) { best_idx = o; best_ov = 2.0f; }
            }
            int cls = (best_ov < THRESH) ? 0 : (int)s_gt[best_idx * 5 + 4];

            float mx = fs[21 * j];
#pragma unroll
            for (int c = 1; c < NC; c++) mx = fmaxf(mx, fs[21 * j + c]);
            float se = 0.0f;
#pragma unroll
            for (int c = 0; c < NC; c++) se += __expf(fs[21 * j + c] - mx);
            float lse = mx + __logf(se);
            float g = fs[21 * j];
#pragma unroll
            for (int c = 1; c < NC; c++) g = (c == cls) ? fs[21 * j + c] : g;
            float ce = lse - g;

            bool pos = cls > 0;
            mine_v[j] = pos ? 0.0f : ce;

            if (pos) {
                l_np++;
                l_ce += (double)ce;
                float m0 = s_gt[best_idx * 5 + 0], m1 = s_gt[best_idx * 5 + 1];
                float m2 = s_gt[best_idx * 5 + 2], m3 = s_gt[best_idx * 5 + 3];
                float tx = ((m0 + m2) * 0.5f - pr.x) / (0.1f * pr.z);
                float ty = ((m1 + m3) * 0.5f - pr.y) / (0.1f * pr.w);
                float tw = __logf((m2 - m0) / pr.z) * 5.0f;
                float th = __logf((m3 - m1) / pr.w) * 5.0f;
                float4 lp = reinterpret_cast<const float4*>(loc_preds)[(size_t)b * P + p];
                float d0 = fabsf(lp.x - tx), d1 = fabsf(lp.y - ty);
                float d2 = fabsf(lp.z - tw), d3 = fabsf(lp.w - th);
                float s0 = d0 < 1.0f ? 0.5f * d0 * d0 : d0 - 0.5f;
                float s1 = d1 < 1.0f ? 0.5f * d1 * d1 : d1 - 0.5f;
                float s2 = d2 < 1.0f ? 0.5f * d2 * d2 : d2 - 0.5f;
                float s3 = d3 < 1.0f ? 0.5f * d3 * d3 : d3 - 0.5f;
                l_loc += (double)(s0 + s1 + s2 + s3);
            }
        }
        float4 mv = make_float4(mine_v[0], mine_v[1], mine_v[2], mine_v[3]);
        reinterpret_cast<float4*>(mine)[((size_t)b * P + p0) >> 2] = mv;
    }

    // block reduction -> plain partial stores (NO contended atomics)
    const int lane = tid & 63;
    const int wave = tid >> 6;
#pragma unroll
    for (int off = 32; off > 0; off >>= 1) {
        l_loc += __shfl_xor(l_loc, off, 64);
        l_ce  += __shfl_xor(l_ce, off, 64);
        l_np  += __shfl_xor(l_np, off, 64);
    }
    __shared__ double s_loc[4], s_ce[4];
    __shared__ int s_np[4];
    if (lane == 0) { s_loc[wave] = l_loc; s_ce[wave] = l_ce; s_np[wave] = l_np; }
    __syncthreads();
    if (tid == 0) {
        int q = b * NBX + blockIdx.x;
        pl[q] = (s_loc[0] + s_loc[1]) + (s_loc[2] + s_loc[3]);
        pc[q] = (s_ce[0] + s_ce[1]) + (s_ce[2] + s_ce[3]);
        pn[q] = s_np[0] + s_np[1] + s_np[2] + s_np[3];
    }
}

// Mid reduce: sum 1152 partials -> acc[0..1], num_pos[b], total_pos. One block.
__global__ void __launch_bounds__(1024) k_mid(const double* __restrict__ pl,
                                              const double* __restrict__ pc,
                                              const int* __restrict__ pn,
                                              double* __restrict__ acc,
                                              int* __restrict__ num_pos,
                                              u32* __restrict__ total_pos) {
    const int tid = threadIdx.x;
    const int lane = tid & 63, wave = tid >> 6;
    __shared__ double s_l[16], s_c[16];
    __shared__ int s_t[2];

    double tl = 0.0, tc = 0.0;
    for (int i = tid; i < NPART; i += 1024) { tl += pl[i]; tc += pc[i]; }
#pragma unroll
    for (int off = 32; off > 0; off >>= 1) {
        tl += __shfl_xor(tl, off, 64);
        tc += __shfl_xor(tc, off, 64);
    }
    if (lane == 0) { s_l[wave] = tl; s_c[wave] = tc; }

    int npb = 0;
    if (tid < B) {
#pragma unroll
        for (int x = 0; x < NBX; x++) npb += pn[tid * NBX + x];
        num_pos[tid] = npb;
    }
    if (tid < B) {
        int t = npb;
#pragma unroll
        for (int off = 32; off > 0; off >>= 1) t += __shfl_xor(t, off, 64);
        if (lane == 0) s_t[wave] = t;
    }
    __syncthreads();
    if (tid == 0) {
        double al = 0.0, ac = 0.0;
#pragma unroll
        for (int w = 0; w < 16; w++) { al += s_l[w]; ac += s_c[w]; }
        acc[0] = al;
        acc[1] = ac;
        *total_pos = (u32)(s_t[0] + s_t[1]);
    }
}

// Top-k sum via radix select (wave-parallel bin scan) + fused finalize.
__global__ void __launch_bounds__(1024) k_hardneg(const float* __restrict__ mine,
                                                  const int* __restrict__ num_pos,
                                                  const u32* __restrict__ total_pos,
                                                  double* __restrict__ acc,
                                                  u32* __restrict__ ticket,
                                                  float* __restrict__ out) {
    const int b = blockIdx.x;
    const int tid = threadIdx.x;
    __shared__ float s_mine[P];
    __shared__ u32 s_hist[256];
    __shared__ u32 s_sel[2];
    __shared__ double s_red[16];

    const int tp = (int)*total_pos;
    const int np = num_pos[b];
    int k = 3 * np;
    int cap = P - tp - 1;
    if (cap < k) k = cap;

    if (k > 0) {
        for (int i = tid; i < P; i += 1024) s_mine[i] = mine[(size_t)b * P + i];
        if (tid == 0) { s_sel[0] = 0u; s_sel[1] = (u32)k; }
        __syncthreads();

        for (int shift = 24; shift >= 0; shift -= 8) {
            if (tid < 256) s_hist[tid] = 0u;
            __syncthreads();
            u32 prefix = s_sel[0];
            u32 kr = s_sel[1];
            u32 himask = (shift == 24) ? 0u : (0xFFFFFFFFu << (shift + 8));
            for (int i = tid; i < P; i += 1024) {
                u32 v = __float_as_uint(s_mine[i]);
                if ((v & himask) == prefix) atomicAdd(&s_hist[(v >> shift) & 255u], 1u);
            }
            __syncthreads();
            if (tid < 64) {
                const int L = tid;
                const int btop = 255 - 4 * L;
                u32 h0 = s_hist[btop], h1 = s_hist[btop - 1], h2 = s_hist[btop - 2], h3 = s_hist[btop - 3];
                u32 g4 = h0 + h1 + h2 + h3;
                u32 x = g4;
#pragma unroll
                for (int off = 1; off < 64; off <<= 1) {
                    u32 v = __shfl_up(x, off, 64);
                    if (L >= off) x += v;
                }
                u32 excl = x - g4;
                if (excl < kr && excl + g4 >= kr) {
                    u32 c = excl; int chosen = btop; u32 kloc = kr;
                    u32 nc;
                    nc = c + h0; if (c < kr && nc >= kr) { chosen = btop;     kloc = kr - c; } c = nc;
                    nc = c + h1; if (c < kr && nc >= kr) { chosen = btop - 1; kloc = kr - c; } c = nc;
                    nc = c + h2; if (c < kr && nc >= kr) { chosen = btop - 2; kloc = kr - c; } c = nc;
                    nc = c + h3; if (c < kr && nc >= kr) { chosen = btop - 3; kloc = kr - c; } c = nc;
                    s_sel[0] = prefix | ((u32)chosen << shift);
                    s_sel[1] = kloc;
                }
            }
            __syncthreads();
        }

        u32 tbits = s_sel[0];
        u32 kr = s_sel[1];
        float T = __uint_as_float(tbits);

        double sd = 0.0;
        for (int i = tid; i < P; i += 1024) {
            u32 v = __float_as_uint(s_mine[i]);
            if (v > tbits) sd += (double)s_mine[i];
        }
        const int lane = tid & 63;
        const int wave = tid >> 6;
#pragma unroll
        for (int off = 32; off > 0; off >>= 1) sd += __shfl_xor(sd, off, 64);
        if (lane == 0) s_red[wave] = sd;
        __syncthreads();
        if (tid == 0) {
            double tt = 0.0;
#pragma unroll
            for (int w = 0; w < 16; w++) tt += s_red[w];
            atomicAdd(&acc[2], tt + (double)kr * (double)T);
        }
    }

    __threadfence();
    __syncthreads();
    if (tid == 0) {
        u32 old = atomicAdd(ticket, 1u);
        if (old == B - 1) {
            __threadfence();
            double a0 = atomicAdd(&acc[0], 0.0);
            double a1 = atomicAdd(&acc[1], 0.0);
            double a2 = atomicAdd(&acc[2], 0.0);
            double n = (double)tp;
            out[0] = (float)(a0 / n);
            out[1] = (float)((a1 + a2) / n);
        }
    }
}

extern "C" void kernel_launch(void* const* d_in, const int* in_sizes, int n_in,
                              void* d_out, int out_size, void* d_ws, size_t ws_size,
                              hipStream_t stream) {
    const float* loc_preds = (const float*)d_in[0];
    const float* scores    = (const float*)d_in[1];
    const float* gt        = (const float*)d_in[2];
    const float* priors    = (const float*)d_in[3];

    char* ws = (char*)d_ws;
    double* acc    = (double*)ws;            // [0,24): loc, ce_pos, neg_sum
    u32* total_pos = (u32*)(ws + 24);        // [24,28)
    u32* ticket    = (u32*)(ws + 28);        // [28,32)
    int* num_pos   = (int*)(ws + 32);        // [32,544)
    u64* bestkey   = (u64*)(ws + 544);       // [544,16928)
    double* pl     = (double*)(ws + 16960);  // [16960,26176)
    double* pc     = (double*)(ws + 26176);  // [26176,35392)
    int* pn        = (int*)(ws + 35392);     // [35392,40000)
    float* mine    = (float*)(ws + 40000);   // B*P*4

    hipMemsetAsync(d_ws, 0, 16960, stream);

    k_pass1<<<dim3(8, B), dim3(256), 0, stream>>>(gt, priors, bestkey);
    k_pass2<<<dim3(NBX, B), dim3(256), 0, stream>>>(
        gt, priors, bestkey, loc_preds, scores, mine, pl, pc, pn);
    k_mid<<<dim3(1), dim3(1024), 0, stream>>>(pl, pc, pn, acc, num_pos, total_pos);
    k_hardneg<<<dim3(B), dim3(1024), 0, stream>>>(mine, num_pos, total_pos, acc,
                                                  ticket, (float*)d_out);
}

// Round 9
// 71.435 us; speedup vs baseline: 3.3722x; 1.4791x over previous
//
#include <hip/hip_runtime.h>
#include <cstdint>
#include <cstddef>

#define B 128
#define P 8732
#define NC 21
#define O 16
#define THRESH 0.5f
#define QPI 2183   // quads per image = P/4
#define NBX 9      // pass2 blocks per image
#define NPART (B * NBX)
#define NB1 8      // pass1 blocks per image

typedef unsigned long long u64;
typedef unsigned int u32;

__device__ __forceinline__ float iou_pt(float a0, float a1, float a2, float a3,
                                        float b0, float b1, float b2, float b3) {
    float ltx = fmaxf(a0, b0), lty = fmaxf(a1, b1);
    float rbx = fminf(a2, b2), rby = fminf(a3, b3);
    float wx = fmaxf(rbx - ltx, 0.0f), wy = fmaxf(rby - lty, 0.0f);
    float inter = wx * wy;
    float aa = (a2 - a0) * (a3 - a1);
    float ab = (b2 - b0) * (b3 - b1);
    return inter / (aa + ab - inter);
}

// Pass 1: per-object best prior partial max per block -> PLAIN stores
// (bk[(b*O+o)*NB1 + blk]); no atomics, no init required.
__global__ void __launch_bounds__(256) k_pass1(const float* __restrict__ gt,
                                               const float* __restrict__ priors,
                                               u64* __restrict__ bk) {
    const int b = blockIdx.y;
    __shared__ float s_gt[O * 4];
    __shared__ u64 s_wk[4][O];
    const int tid = threadIdx.x;
    const int wave = tid >> 6, lane = tid & 63;
    if (tid < O * 4) {
        int o = tid >> 2, c = tid & 3;
        s_gt[tid] = gt[(b * O + o) * 5 + c];
    }
    __syncthreads();

    u64 lk[O];
#pragma unroll
    for (int o = 0; o < O; o++) lk[o] = 0ull;

    for (int p = blockIdx.x * 256 + tid; p < P; p += NB1 * 256) {
        float4 pr = reinterpret_cast<const float4*>(priors)[p];
        float b0 = pr.x - pr.z * 0.5f, b1 = pr.y - pr.w * 0.5f;
        float b2 = pr.x + pr.z * 0.5f, b3 = pr.y + pr.w * 0.5f;
#pragma unroll
        for (int o = 0; o < O; o++) {
            float v = iou_pt(s_gt[o * 4 + 0], s_gt[o * 4 + 1], s_gt[o * 4 + 2], s_gt[o * 4 + 3],
                             b0, b1, b2, b3);
            u64 key = ((u64)__float_as_uint(v) << 32) | (u64)(0xFFFFFFFFu - (u32)p);
            lk[o] = (key > lk[o]) ? key : lk[o];
        }
    }

#pragma unroll
    for (int o = 0; o < O; o++) {
        u64 k = lk[o];
#pragma unroll
        for (int off = 32; off > 0; off >>= 1) {
            u64 other = (u64)__shfl_xor((long long)k, off, 64);
            k = (other > k) ? other : k;
        }
        if (lane == 0) s_wk[wave][o] = k;
    }
    __syncthreads();
    if (tid < O) {
        u64 k = s_wk[0][tid];
#pragma unroll
        for (int w = 1; w < 4; w++) { u64 v = s_wk[w][tid]; k = (v > k) ? v : k; }
        bk[((size_t)b * O + tid) * NB1 + blockIdx.x] = k;
    }
}

// Pass 2: R8 structure (4 priors/thread, 21 float4 register loads, plain
// partial stores); s_bp derived by maxing pass1's 8 partial keys.
__global__ void __launch_bounds__(256) k_pass2(const float* __restrict__ gt,
                                               const float* __restrict__ priors,
                                               const u64* __restrict__ bk,
                                               const float* __restrict__ loc_preds,
                                               const float* __restrict__ scores,
                                               float* __restrict__ mine,
                                               double* __restrict__ pl,
                                               double* __restrict__ pc,
                                               int* __restrict__ pn) {
    const int b = blockIdx.y;
    __shared__ float s_gt[O * 5];
    __shared__ int s_bp[O];
    const int tid = threadIdx.x;
    if (tid < O * 5) s_gt[tid] = gt[b * O * 5 + tid];
    if (tid < O) {
        u64 k = bk[((size_t)b * O + tid) * NB1];
#pragma unroll
        for (int i = 1; i < NB1; i++) {
            u64 v = bk[((size_t)b * O + tid) * NB1 + i];
            k = (v > k) ? v : k;
        }
        s_bp[tid] = (int)(0xFFFFFFFFu - (u32)(k & 0xFFFFFFFFull));
    }
    __syncthreads();

    const int gq = blockIdx.x * 256 + tid;  // quad index within image
    double l_loc = 0.0, l_ce = 0.0;
    int l_np = 0;

    if (gq < QPI) {
        const int p0 = gq * 4;
        float fs[84];
        const float4* s4 = reinterpret_cast<const float4*>(scores)
                           + (size_t)b * (size_t)(P * NC / 4) + (size_t)21 * gq;
#pragma unroll
        for (int i = 0; i < 21; i++) {
            float4 v = s4[i];
            fs[4 * i + 0] = v.x; fs[4 * i + 1] = v.y;
            fs[4 * i + 2] = v.z; fs[4 * i + 3] = v.w;
        }
        float4 pr4[4];
#pragma unroll
        for (int j = 0; j < 4; j++) pr4[j] = reinterpret_cast<const float4*>(priors)[p0 + j];

        float mine_v[4];

#pragma unroll
        for (int j = 0; j < 4; j++) {
            const int p = p0 + j;
            const float4 pr = pr4[j];
            float pb0 = pr.x - pr.z * 0.5f, pb1 = pr.y - pr.w * 0.5f;
            float pb2 = pr.x + pr.z * 0.5f, pb3 = pr.y + pr.w * 0.5f;

            float best_ov = -1.0f;
            int best_idx = 0;
#pragma unroll
            for (int o = 0; o < O; o++) {
                float v = iou_pt(s_gt[o * 5 + 0], s_gt[o * 5 + 1], s_gt[o * 5 + 2], s_gt[o * 5 + 3],
                                 pb0, pb1, pb2, pb3);
                if (v > best_ov) { best_ov = v; best_idx = o; }
            }
#pragma unroll
            for (int o = 0; o < O; o++) {
                if (s_bp[o] == p) { best_idx = o; best_ov = 2.0f; }
            }
            int cls = (best_ov < THRESH) ? 0 : (int)s_gt[best_idx * 5 + 4];

            float mx = fs[21 * j];
#pragma unroll
            for (int c = 1; c < NC; c++) mx = fmaxf(mx, fs[21 * j + c]);
            float se = 0.0f;
#pragma unroll
            for (int c = 0; c < NC; c++) se += __expf(fs[21 * j + c] - mx);
            float lse = mx + __logf(se);
            float g = fs[21 * j];
#pragma unroll
            for (int c = 1; c < NC; c++) g = (c == cls) ? fs[21 * j + c] : g;
            float ce = lse - g;

            bool pos = cls > 0;
            mine_v[j] = pos ? 0.0f : ce;

            if (pos) {
                l_np++;
                l_ce += (double)ce;
                float m0 = s_gt[best_idx * 5 + 0], m1 = s_gt[best_idx * 5 + 1];
                float m2 = s_gt[best_idx * 5 + 2], m3 = s_gt[best_idx * 5 + 3];
                float tx = ((m0 + m2) * 0.5f - pr.x) / (0.1f * pr.z);
                float ty = ((m1 + m3) * 0.5f - pr.y) / (0.1f * pr.w);
                float tw = __logf((m2 - m0) / pr.z) * 5.0f;
                float th = __logf((m3 - m1) / pr.w) * 5.0f;
                float4 lp = reinterpret_cast<const float4*>(loc_preds)[(size_t)b * P + p];
                float d0 = fabsf(lp.x - tx), d1 = fabsf(lp.y - ty);
                float d2 = fabsf(lp.z - tw), d3 = fabsf(lp.w - th);
                float s0 = d0 < 1.0f ? 0.5f * d0 * d0 : d0 - 0.5f;
                float s1 = d1 < 1.0f ? 0.5f * d1 * d1 : d1 - 0.5f;
                float s2 = d2 < 1.0f ? 0.5f * d2 * d2 : d2 - 0.5f;
                float s3 = d3 < 1.0f ? 0.5f * d3 * d3 : d3 - 0.5f;
                l_loc += (double)(s0 + s1 + s2 + s3);
            }
        }
        float4 mv = make_float4(mine_v[0], mine_v[1], mine_v[2], mine_v[3]);
        reinterpret_cast<float4*>(mine)[((size_t)b * P + p0) >> 2] = mv;
    }

    const int lane = tid & 63;
    const int wave = tid >> 6;
#pragma unroll
    for (int off = 32; off > 0; off >>= 1) {
        l_loc += __shfl_xor(l_loc, off, 64);
        l_ce  += __shfl_xor(l_ce, off, 64);
        l_np  += __shfl_xor(l_np, off, 64);
    }
    __shared__ double s_loc[4], s_ce[4];
    __shared__ int s_np[4];
    if (lane == 0) { s_loc[wave] = l_loc; s_ce[wave] = l_ce; s_np[wave] = l_np; }
    __syncthreads();
    if (tid == 0) {
        int q = b * NBX + blockIdx.x;
        pl[q] = (s_loc[0] + s_loc[1]) + (s_loc[2] + s_loc[3]);
        pc[q] = (s_ce[0] + s_ce[1]) + (s_ce[2] + s_ce[3]);
        pn[q] = s_np[0] + s_np[1] + s_np[2] + s_np[3];
    }
}

// Hard-negative top-k sum. Each block self-computes total_pos (redundant sum
// of the 1152 pn partials) and its own num_pos -> no serial mid-kernel.
// Plain-stores per-image neg sum. No atomics anywhere.
__global__ void __launch_bounds__(1024) k_hardneg(const float* __restrict__ mine,
                                                  const int* __restrict__ pn,
                                                  double* __restrict__ pneg) {
    const int b = blockIdx.x;
    const int tid = threadIdx.x;
    const int lane = tid & 63, wave = tid >> 6;
    __shared__ float s_mine[P];
    __shared__ u32 s_hist[256];
    __shared__ u32 s_sel[2];
    __shared__ double s_red[16];
    __shared__ int s_ti[16];
    __shared__ int s_np9[NBX];
    __shared__ int s_k;

    // total_pos: redundant block-wide sum of all partials
    {
        int t = 0;
        for (int i = tid; i < NPART; i += 1024) t += pn[i];
#pragma unroll
        for (int off = 32; off > 0; off >>= 1) t += __shfl_xor(t, off, 64);
        if (lane == 0) s_ti[wave] = t;
    }
    if (tid < NBX) s_np9[tid] = pn[b * NBX + tid];
    __syncthreads();
    if (tid == 0) {
        int tp = 0;
#pragma unroll
        for (int w = 0; w < 16; w++) tp += s_ti[w];
        int np = 0;
#pragma unroll
        for (int x = 0; x < NBX; x++) np += s_np9[x];
        int k = 3 * np;
        int cap = P - tp - 1;
        if (cap < k) k = cap;
        s_k = k;
    }
    __syncthreads();
    const int k = s_k;

    if (k <= 0) {
        if (tid == 0) pneg[b] = 0.0;
        return;
    }

    for (int i = tid; i < P; i += 1024) s_mine[i] = mine[(size_t)b * P + i];
    if (tid == 0) { s_sel[0] = 0u; s_sel[1] = (u32)k; }
    __syncthreads();

    for (int shift = 24; shift >= 0; shift -= 8) {
        if (tid < 256) s_hist[tid] = 0u;
        __syncthreads();
        u32 prefix = s_sel[0];
        u32 kr = s_sel[1];
        u32 himask = (shift == 24) ? 0u : (0xFFFFFFFFu << (shift + 8));
        for (int i = tid; i < P; i += 1024) {
            u32 v = __float_as_uint(s_mine[i]);
            if ((v & himask) == prefix) atomicAdd(&s_hist[(v >> shift) & 255u], 1u);
        }
        __syncthreads();
        if (tid < 64) {
            const int L = tid;
            const int btop = 255 - 4 * L;
            u32 h0 = s_hist[btop], h1 = s_hist[btop - 1], h2 = s_hist[btop - 2], h3 = s_hist[btop - 3];
            u32 g4 = h0 + h1 + h2 + h3;
            u32 x = g4;
#pragma unroll
            for (int off = 1; off < 64; off <<= 1) {
                u32 v = __shfl_up(x, off, 64);
                if (L >= off) x += v;
            }
            u32 excl = x - g4;
            if (excl < kr && excl + g4 >= kr) {
                u32 c = excl; int chosen = btop; u32 kloc = kr;
                u32 nc;
                nc = c + h0; if (c < kr && nc >= kr) { chosen = btop;     kloc = kr - c; } c = nc;
                nc = c + h1; if (c < kr && nc >= kr) { chosen = btop - 1; kloc = kr - c; } c = nc;
                nc = c + h2; if (c < kr && nc >= kr) { chosen = btop - 2; kloc = kr - c; } c = nc;
                nc = c + h3; if (c < kr && nc >= kr) { chosen = btop - 3; kloc = kr - c; } c = nc;
                s_sel[0] = prefix | ((u32)chosen << shift);
                s_sel[1] = kloc;
            }
        }
        __syncthreads();
    }

    u32 tbits = s_sel[0];
    u32 kr = s_sel[1];
    float T = __uint_as_float(tbits);

    double sd = 0.0;
    for (int i = tid; i < P; i += 1024) {
        u32 v = __float_as_uint(s_mine[i]);
        if (v > tbits) sd += (double)s_mine[i];
    }
#pragma unroll
    for (int off = 32; off > 0; off >>= 1) sd += __shfl_xor(sd, off, 64);
    if (lane == 0) s_red[wave] = sd;
    __syncthreads();
    if (tid == 0) {
        double tt = 0.0;
#pragma unroll
        for (int w = 0; w < 16; w++) tt += s_red[w];
        pneg[b] = tt + (double)kr * (double)T;
    }
}

// Final: sum all partials, write both outputs. One small block at the end.
__global__ void __launch_bounds__(1024) k_fin(const double* __restrict__ pl,
                                              const double* __restrict__ pc,
                                              const int* __restrict__ pn,
                                              const double* __restrict__ pneg,
                                              float* __restrict__ out) {
    const int tid = threadIdx.x;
    const int lane = tid & 63, wave = tid >> 6;
    __shared__ double s_l[16], s_c[16], s_g[16];
    __shared__ int s_t[16];

    double tl = 0.0, tc = 0.0, tg = 0.0;
    int tn = 0;
    for (int i = tid; i < NPART; i += 1024) { tl += pl[i]; tc += pc[i]; tn += pn[i]; }
    if (tid < B) tg = pneg[tid];
#pragma unroll
    for (int off = 32; off > 0; off >>= 1) {
        tl += __shfl_xor(tl, off, 64);
        tc += __shfl_xor(tc, off, 64);
        tg += __shfl_xor(tg, off, 64);
        tn += __shfl_xor(tn, off, 64);
    }
    if (lane == 0) { s_l[wave] = tl; s_c[wave] = tc; s_g[wave] = tg; s_t[wave] = tn; }
    __syncthreads();
    if (tid == 0) {
        double al = 0.0, ac = 0.0, ag = 0.0;
        int an = 0;
#pragma unroll
        for (int w = 0; w < 16; w++) { al += s_l[w]; ac += s_c[w]; ag += s_g[w]; an += s_t[w]; }
        double n = (double)an;
        out[0] = (float)(al / n);
        out[1] = (float)((ac + ag) / n);
    }
}

extern "C" void kernel_launch(void* const* d_in, const int* in_sizes, int n_in,
                              void* d_out, int out_size, void* d_ws, size_t ws_size,
                              hipStream_t stream) {
    const float* loc_preds = (const float*)d_in[0];
    const float* scores    = (const float*)d_in[1];
    const float* gt        = (const float*)d_in[2];
    const float* priors    = (const float*)d_in[3];

    char* ws = (char*)d_ws;
    u64* bk      = (u64*)ws;                 // [0, 131072)  B*O*NB1 u64
    double* pl   = (double*)(ws + 131072);   // [131072, 140288)
    double* pc   = (double*)(ws + 140288);   // [140288, 149504)
    int* pn      = (int*)(ws + 149504);      // [149504, 154112)
    double* pneg = (double*)(ws + 154112);   // [154112, 155136)
    float* mine  = (float*)(ws + 155136);    // B*P*4

    // no memset needed: every ws slot consumed is plainly overwritten each call

    k_pass1<<<dim3(NB1, B), dim3(256), 0, stream>>>(gt, priors, bk);
    k_pass2<<<dim3(NBX, B), dim3(256), 0, stream>>>(
        gt, priors, bk, loc_preds, scores, mine, pl, pc, pn);
    k_hardneg<<<dim3(B), dim3(1024), 0, stream>>>(mine, pn, pneg);
    k_fin<<<dim3(1), dim3(1024), 0, stream>>>(pl, pc, pn, pneg, (float*)d_out);
}

// Round 10
// 59.405 us; speedup vs baseline: 4.0551x; 1.2025x over previous
//
#include <hip/hip_runtime.h>
#include <cstdint>
#include <cstddef>

#define B 128
#define P 8732
#define NC 21
#define O 16
#define THRESH 0.5f
#define QPI 2183   // quads per image = P/4
#define NBX 9      // pass2 blocks per image
#define NPART (B * NBX)
#define NB1 8      // pass1 blocks per image

typedef unsigned long long u64;
typedef unsigned int u32;
typedef unsigned char u8;

__device__ __forceinline__ float iou_pt(float a0, float a1, float a2, float a3,
                                        float b0, float b1, float b2, float b3) {
    float ltx = fmaxf(a0, b0), lty = fmaxf(a1, b1);
    float rbx = fminf(a2, b2), rby = fminf(a3, b3);
    float wx = fmaxf(rbx - ltx, 0.0f), wy = fmaxf(rby - lty, 0.0f);
    float inter = wx * wy;
    float aa = (a2 - a0) * (a3 - a1);
    float ab = (b2 - b0) * (b3 - b1);
    return inter / (aa + ab - inter);
}

// Pass 1: per-object best-prior partial max (plain stores, no atomics) AND
// per-prior packed best-truth byte: idx | (ov>=THRESH ? 0x80 : 0).
__global__ void __launch_bounds__(256) k_pass1(const float* __restrict__ gt,
                                               const float* __restrict__ priors,
                                               u64* __restrict__ bk,
                                               u8* __restrict__ bidx) {
    const int b = blockIdx.y;
    __shared__ float s_gt[O * 4];
    __shared__ u64 s_wk[4][O];
    const int tid = threadIdx.x;
    const int wave = tid >> 6, lane = tid & 63;
    if (tid < O * 4) {
        int o = tid >> 2, c = tid & 3;
        s_gt[tid] = gt[(b * O + o) * 5 + c];
    }
    __syncthreads();

    u64 lk[O];
#pragma unroll
    for (int o = 0; o < O; o++) lk[o] = 0ull;

    for (int p = blockIdx.x * 256 + tid; p < P; p += NB1 * 256) {
        float4 pr = reinterpret_cast<const float4*>(priors)[p];
        float b0 = pr.x - pr.z * 0.5f, b1 = pr.y - pr.w * 0.5f;
        float b2 = pr.x + pr.z * 0.5f, b3 = pr.y + pr.w * 0.5f;
        float bov = -1.0f; int bo = 0;
#pragma unroll
        for (int o = 0; o < O; o++) {
            float v = iou_pt(s_gt[o * 4 + 0], s_gt[o * 4 + 1], s_gt[o * 4 + 2], s_gt[o * 4 + 3],
                             b0, b1, b2, b3);
            u64 key = ((u64)__float_as_uint(v) << 32) | (u64)(0xFFFFFFFFu - (u32)p);
            lk[o] = (key > lk[o]) ? key : lk[o];
            if (v > bov) { bov = v; bo = o; }   // first occurrence on tie
        }
        bidx[(size_t)b * P + p] = (u8)(bo | ((bov >= THRESH) ? 0x80 : 0));
    }

#pragma unroll
    for (int o = 0; o < O; o++) {
        u64 k = lk[o];
#pragma unroll
        for (int off = 32; off > 0; off >>= 1) {
            u64 other = (u64)__shfl_xor((long long)k, off, 64);
            k = (other > k) ? other : k;
        }
        if (lane == 0) s_wk[wave][o] = k;
    }
    __syncthreads();
    if (tid < O) {
        u64 k = s_wk[0][tid];
#pragma unroll
        for (int w = 1; w < 4; w++) { u64 v = s_wk[w][tid]; k = (v > k) ? v : k; }
        bk[((size_t)b * O + tid) * NB1 + blockIdx.x] = k;
    }
}

// Pass 2: 4 priors/thread, 21 float4 register loads; match read as one packed
// u32 (4 priors) from pass1 -- no IoU recompute. Plain partial stores.
__global__ void __launch_bounds__(256) k_pass2(const float* __restrict__ gt,
                                               const float* __restrict__ priors,
                                               const u64* __restrict__ bk,
                                               const u8* __restrict__ bidx,
                                               const float* __restrict__ loc_preds,
                                               const float* __restrict__ scores,
                                               float* __restrict__ mine,
                                               double* __restrict__ pl,
                                               double* __restrict__ pc,
                                               int* __restrict__ pn) {
    const int b = blockIdx.y;
    __shared__ float s_gt[O * 5];
    __shared__ int s_bp[O];
    const int tid = threadIdx.x;
    if (tid < O * 5) s_gt[tid] = gt[b * O * 5 + tid];
    if (tid < O) {
        u64 k = bk[((size_t)b * O + tid) * NB1];
#pragma unroll
        for (int i = 1; i < NB1; i++) {
            u64 v = bk[((size_t)b * O + tid) * NB1 + i];
            k = (v > k) ? v : k;
        }
        s_bp[tid] = (int)(0xFFFFFFFFu - (u32)(k & 0xFFFFFFFFull));
    }
    __syncthreads();

    const int gq = blockIdx.x * 256 + tid;  // quad index within image
    double l_loc = 0.0, l_ce = 0.0;
    int l_np = 0;

    if (gq < QPI) {
        const int p0 = gq * 4;
        float fs[84];
        const float4* s4 = reinterpret_cast<const float4*>(scores)
                           + (size_t)b * (size_t)(P * NC / 4) + (size_t)21 * gq;
#pragma unroll
        for (int i = 0; i < 21; i++) {
            float4 v = s4[i];
            fs[4 * i + 0] = v.x; fs[4 * i + 1] = v.y;
            fs[4 * i + 2] = v.z; fs[4 * i + 3] = v.w;
        }
        const u32 mw = *reinterpret_cast<const u32*>(bidx + (size_t)b * P + p0);
        float4 pr4[4];
#pragma unroll
        for (int j = 0; j < 4; j++) pr4[j] = reinterpret_cast<const float4*>(priors)[p0 + j];

        float mine_v[4];

#pragma unroll
        for (int j = 0; j < 4; j++) {
            const int p = p0 + j;
            const float4 pr = pr4[j];

            int e = (int)((mw >> (8 * j)) & 0xFFu);
            int best_idx = e & 0x3F;
            bool matched = (e & 0x80) != 0;
#pragma unroll
            for (int o = 0; o < O; o++) {
                if (s_bp[o] == p) { best_idx = o; matched = true; }   // last wins
            }
            int cls = matched ? (int)s_gt[best_idx * 5 + 4] : 0;

            float mx = fs[21 * j];
#pragma unroll
            for (int c = 1; c < NC; c++) mx = fmaxf(mx, fs[21 * j + c]);
            float se = 0.0f;
#pragma unroll
            for (int c = 0; c < NC; c++) se += __expf(fs[21 * j + c] - mx);
            float lse = mx + __logf(se);
            float g = fs[21 * j];
#pragma unroll
            for (int c = 1; c < NC; c++) g = (c == cls) ? fs[21 * j + c] : g;
            float ce = lse - g;

            bool pos = cls > 0;
            mine_v[j] = pos ? 0.0f : ce;

            if (pos) {
                l_np++;
                l_ce += (double)ce;
                float m0 = s_gt[best_idx * 5 + 0], m1 = s_gt[best_idx * 5 + 1];
                float m2 = s_gt[best_idx * 5 + 2], m3 = s_gt[best_idx * 5 + 3];
                float tx = ((m0 + m2) * 0.5f - pr.x) / (0.1f * pr.z);
                float ty = ((m1 + m3) * 0.5f - pr.y) / (0.1f * pr.w);
                float tw = __logf((m2 - m0) / pr.z) * 5.0f;
                float th = __logf((m3 - m1) / pr.w) * 5.0f;
                float4 lp = reinterpret_cast<const float4*>(loc_preds)[(size_t)b * P + p];
                float d0 = fabsf(lp.x - tx), d1 = fabsf(lp.y - ty);
                float d2 = fabsf(lp.z - tw), d3 = fabsf(lp.w - th);
                float s0 = d0 < 1.0f ? 0.5f * d0 * d0 : d0 - 0.5f;
                float s1 = d1 < 1.0f ? 0.5f * d1 * d1 : d1 - 0.5f;
                float s2 = d2 < 1.0f ? 0.5f * d2 * d2 : d2 - 0.5f;
                float s3 = d3 < 1.0f ? 0.5f * d3 * d3 : d3 - 0.5f;
                l_loc += (double)(s0 + s1 + s2 + s3);
            }
        }
        float4 mv = make_float4(mine_v[0], mine_v[1], mine_v[2], mine_v[3]);
        reinterpret_cast<float4*>(mine)[((size_t)b * P + p0) >> 2] = mv;
    }

    const int lane = tid & 63;
    const int wave = tid >> 6;
#pragma unroll
    for (int off = 32; off > 0; off >>= 1) {
        l_loc += __shfl_xor(l_loc, off, 64);
        l_ce  += __shfl_xor(l_ce, off, 64);
        l_np  += __shfl_xor(l_np, off, 64);
    }
    __shared__ double s_loc[4], s_ce[4];
    __shared__ int s_np[4];
    if (lane == 0) { s_loc[wave] = l_loc; s_ce[wave] = l_ce; s_np[wave] = l_np; }
    __syncthreads();
    if (tid == 0) {
        int q = b * NBX + blockIdx.x;
        pl[q] = (s_loc[0] + s_loc[1]) + (s_loc[2] + s_loc[3]);
        pc[q] = (s_ce[0] + s_ce[1]) + (s_ce[2] + s_ce[3]);
        pn[q] = s_np[0] + s_np[1] + s_np[2] + s_np[3];
    }
}

// Hard-negative top-k sum; self-computes total_pos; plain stores; no atomics.
__global__ void __launch_bounds__(1024) k_hardneg(const float* __restrict__ mine,
                                                  const int* __restrict__ pn,
                                                  double* __restrict__ pneg) {
    const int b = blockIdx.x;
    const int tid = threadIdx.x;
    const int lane = tid & 63, wave = tid >> 6;
    __shared__ float s_mine[P];
    __shared__ u32 s_hist[256];
    __shared__ u32 s_sel[2];
    __shared__ double s_red[16];
    __shared__ int s_ti[16];
    __shared__ int s_np9[NBX];
    __shared__ int s_k;

    {
        int t = 0;
        for (int i = tid; i < NPART; i += 1024) t += pn[i];
#pragma unroll
        for (int off = 32; off > 0; off >>= 1) t += __shfl_xor(t, off, 64);
        if (lane == 0) s_ti[wave] = t;
    }
    if (tid < NBX) s_np9[tid] = pn[b * NBX + tid];
    __syncthreads();
    if (tid == 0) {
        int tp = 0;
#pragma unroll
        for (int w = 0; w < 16; w++) tp += s_ti[w];
        int np = 0;
#pragma unroll
        for (int x = 0; x < NBX; x++) np += s_np9[x];
        int k = 3 * np;
        int cap = P - tp - 1;
        if (cap < k) k = cap;
        s_k = k;
    }
    __syncthreads();
    const int k = s_k;

    if (k <= 0) {
        if (tid == 0) pneg[b] = 0.0;
        return;
    }

    for (int i = tid; i < P; i += 1024) s_mine[i] = mine[(size_t)b * P + i];
    if (tid == 0) { s_sel[0] = 0u; s_sel[1] = (u32)k; }
    __syncthreads();

    for (int shift = 24; shift >= 0; shift -= 8) {
        if (tid < 256) s_hist[tid] = 0u;
        __syncthreads();
        u32 prefix = s_sel[0];
        u32 kr = s_sel[1];
        u32 himask = (shift == 24) ? 0u : (0xFFFFFFFFu << (shift + 8));
        for (int i = tid; i < P; i += 1024) {
            u32 v = __float_as_uint(s_mine[i]);
            if ((v & himask) == prefix) atomicAdd(&s_hist[(v >> shift) & 255u], 1u);
        }
        __syncthreads();
        if (tid < 64) {
            const int L = tid;
            const int btop = 255 - 4 * L;
            u32 h0 = s_hist[btop], h1 = s_hist[btop - 1], h2 = s_hist[btop - 2], h3 = s_hist[btop - 3];
            u32 g4 = h0 + h1 + h2 + h3;
            u32 x = g4;
#pragma unroll
            for (int off = 1; off < 64; off <<= 1) {
                u32 v = __shfl_up(x, off, 64);
                if (L >= off) x += v;
            }
            u32 excl = x - g4;
            if (excl < kr && excl + g4 >= kr) {
                u32 c = excl; int chosen = btop; u32 kloc = kr;
                u32 nc;
                nc = c + h0; if (c < kr && nc >= kr) { chosen = btop;     kloc = kr - c; } c = nc;
                nc = c + h1; if (c < kr && nc >= kr) { chosen = btop - 1; kloc = kr - c; } c = nc;
                nc = c + h2; if (c < kr && nc >= kr) { chosen = btop - 2; kloc = kr - c; } c = nc;
                nc = c + h3; if (c < kr && nc >= kr) { chosen = btop - 3; kloc = kr - c; } c = nc;
                s_sel[0] = prefix | ((u32)chosen << shift);
                s_sel[1] = kloc;
            }
        }
        __syncthreads();
    }

    u32 tbits = s_sel[0];
    u32 kr = s_sel[1];
    float T = __uint_as_float(tbits);

    double sd = 0.0;
    for (int i = tid; i < P; i += 1024) {
        u32 v = __float_as_uint(s_mine[i]);
        if (v > tbits) sd += (double)s_mine[i];
    }
#pragma unroll
    for (int off = 32; off > 0; off >>= 1) sd += __shfl_xor(sd, off, 64);
    if (lane == 0) s_red[wave] = sd;
    __syncthreads();
    if (tid == 0) {
        double tt = 0.0;
#pragma unroll
        for (int w = 0; w < 16; w++) tt += s_red[w];
        pneg[b] = tt + (double)kr * (double)T;
    }
}

// Final: sum all partials, write both outputs.
__global__ void __launch_bounds__(1024) k_fin(const double* __restrict__ pl,
                                              const double* __restrict__ pc,
                                              const int* __restrict__ pn,
                                              const double* __restrict__ pneg,
                                              float* __restrict__ out) {
    const int tid = threadIdx.x;
    const int lane = tid & 63, wave = tid >> 6;
    __shared__ double s_l[16], s_c[16], s_g[16];
    __shared__ int s_t[16];

    double tl = 0.0, tc = 0.0, tg = 0.0;
    int tn = 0;
    for (int i = tid; i < NPART; i += 1024) { tl += pl[i]; tc += pc[i]; tn += pn[i]; }
    if (tid < B) tg = pneg[tid];
#pragma unroll
    for (int off = 32; off > 0; off >>= 1) {
        tl += __shfl_xor(tl, off, 64);
        tc += __shfl_xor(tc, off, 64);
        tg += __shfl_xor(tg, off, 64);
        tn += __shfl_xor(tn, off, 64);
    }
    if (lane == 0) { s_l[wave] = tl; s_c[wave] = tc; s_g[wave] = tg; s_t[wave] = tn; }
    __syncthreads();
    if (tid == 0) {
        double al = 0.0, ac = 0.0, ag = 0.0;
        int an = 0;
#pragma unroll
        for (int w = 0; w < 16; w++) { al += s_l[w]; ac += s_c[w]; ag += s_g[w]; an += s_t[w]; }
        double n = (double)an;
        out[0] = (float)(al / n);
        out[1] = (float)((ac + ag) / n);
    }
}

extern "C" void kernel_launch(void* const* d_in, const int* in_sizes, int n_in,
                              void* d_out, int out_size, void* d_ws, size_t ws_size,
                              hipStream_t stream) {
    const float* loc_preds = (const float*)d_in[0];
    const float* scores    = (const float*)d_in[1];
    const float* gt        = (const float*)d_in[2];
    const float* priors    = (const float*)d_in[3];

    char* ws = (char*)d_ws;
    u64* bk      = (u64*)ws;                  // [0, 131072)   B*O*NB1 u64
    double* pl   = (double*)(ws + 131072);    // [131072, 140288)
    double* pc   = (double*)(ws + 140288);    // [140288, 149504)
    int* pn      = (int*)(ws + 149504);       // [149504, 154112)
    double* pneg = (double*)(ws + 154112);    // [154112, 155136)
    u8* bidx     = (u8*)(ws + 155136);        // [155136, 1272832)  B*P u8
    float* mine  = (float*)(ws + 1272832);    // B*P*4 (16B-aligned)

    // no memset needed: every ws slot consumed is plainly overwritten each call

    k_pass1<<<dim3(NB1, B), dim3(256), 0, stream>>>(gt, priors, bk, bidx);
    k_pass2<<<dim3(NBX, B), dim3(256), 0, stream>>>(
        gt, priors, bk, bidx, loc_preds, scores, mine, pl, pc, pn);
    k_hardneg<<<dim3(B), dim3(1024), 0, stream>>>(mine, pn, pneg);
    k_fin<<<dim3(1), dim3(1024), 0, stream>>>(pl, pc, pn, pneg, (float*)d_out);
}

// Round 12
// 58.267 us; speedup vs baseline: 4.1343x; 1.0195x over previous
//
#include <hip/hip_runtime.h>
#include <cstdint>
#include <cstddef>

#define B 128
#define P 8732
#define NC 21
#define O 16
#define THRESH 0.5f
#define NB1 8      // pass1 blocks per image
#define NBX2 6     // pass2 blocks per image
#define BPB 1456   // priors per pass2 block
#define WPW 364    // priors per wave
#define NPART (B * NBX2)
#define SLABF 1536 // padded slab floats: 6 DMA instrs x 64 lanes x 4 floats

typedef unsigned long long u64;
typedef unsigned int u32;
typedef unsigned char u8;

__device__ __forceinline__ float iou_pt(float a0, float a1, float a2, float a3,
                                        float b0, float b1, float b2, float b3) {
    float ltx = fmaxf(a0, b0), lty = fmaxf(a1, b1);
    float rbx = fminf(a2, b2), rby = fminf(a3, b3);
    float wx = fmaxf(rbx - ltx, 0.0f), wy = fmaxf(rby - lty, 0.0f);
    float inter = wx * wy;
    float aa = (a2 - a0) * (a3 - a1);
    float ab = (b2 - b0) * (b3 - b1);
    return inter / (aa + ab - inter);
}

// Pass 1: per-object best-prior partial max (plain stores) AND per-prior
// packed best-truth byte: idx | (ov>=THRESH ? 0x80 : 0).
__global__ void __launch_bounds__(256) k_pass1(const float* __restrict__ gt,
                                               const float* __restrict__ priors,
                                               u64* __restrict__ bk,
                                               u8* __restrict__ bidx) {
    const int b = blockIdx.y;
    __shared__ float s_gt[O * 4];
    __shared__ u64 s_wk[4][O];
    const int tid = threadIdx.x;
    const int wave = tid >> 6, lane = tid & 63;
    if (tid < O * 4) {
        int o = tid >> 2, c = tid & 3;
        s_gt[tid] = gt[(b * O + o) * 5 + c];
    }
    __syncthreads();

    u64 lk[O];
#pragma unroll
    for (int o = 0; o < O; o++) lk[o] = 0ull;

    for (int p = blockIdx.x * 256 + tid; p < P; p += NB1 * 256) {
        float4 pr = reinterpret_cast<const float4*>(priors)[p];
        float b0 = pr.x - pr.z * 0.5f, b1 = pr.y - pr.w * 0.5f;
        float b2 = pr.x + pr.z * 0.5f, b3 = pr.y + pr.w * 0.5f;
        float bov = -1.0f; int bo = 0;
#pragma unroll
        for (int o = 0; o < O; o++) {
            float v = iou_pt(s_gt[o * 4 + 0], s_gt[o * 4 + 1], s_gt[o * 4 + 2], s_gt[o * 4 + 3],
                             b0, b1, b2, b3);
            u64 key = ((u64)__float_as_uint(v) << 32) | (u64)(0xFFFFFFFFu - (u32)p);
            lk[o] = (key > lk[o]) ? key : lk[o];
            if (v > bov) { bov = v; bo = o; }   // first occurrence on tie
        }
        bidx[(size_t)b * P + p] = (u8)(bo | ((bov >= THRESH) ? 0x80 : 0));
    }

#pragma unroll
    for (int o = 0; o < O; o++) {
        u64 k = lk[o];
#pragma unroll
        for (int off = 32; off > 0; off >>= 1) {
            u64 other = (u64)__shfl_xor((long long)k, off, 64);
            k = (other > k) ? other : k;
        }
        if (lane == 0) s_wk[wave][o] = k;
    }
    __syncthreads();
    if (tid < O) {
        u64 k = s_wk[0][tid];
#pragma unroll
        for (int w = 1; w < 4; w++) { u64 v = s_wk[w][tid]; k = (v > k) ? v : k; }
        bk[((size_t)b * O + tid) * NB1 + blockIdx.x] = k;
    }
}

// Stage one 64-prior score chunk into a wave-private padded LDS slab via
// global_load_lds DMA. All 6 instructions always issue with all lanes
// (vmcnt increments exact). LDS dest is base+lane*16 UNCONDITIONALLY, so
// the slab must hold 6*1024=6144 B (SLABF floats); overflow lands in the
// never-read pad. Clamped global sources keep reads in-bounds.
__device__ __forceinline__ void stage64(const float* __restrict__ gsrc,
                                        float* lds, int nf4, int lane) {
    const char* src = (const char*)gsrc;
    char* dst = (char*)lds;
#pragma unroll
    for (int i = 0; i < 6; i++) {
        int idx = i * 64 + lane;
        if (idx >= nf4) idx = nf4 - 1;
        __builtin_amdgcn_global_load_lds(
            (const __attribute__((address_space(1))) u32*)(src + (size_t)idx * 16),
            (__attribute__((address_space(3))) u32*)(dst + i * 1024),
            16, 0, 0);
    }
}

// Pass 2: wave-synchronous double-buffered DMA pipeline. Coalesced score
// supply (16 lines per vmem instr, no VGPR round-trip), counted vmcnt(6) so
// the next chunk's loads fly under the current chunk's compute. No atomics.
__global__ void __launch_bounds__(256) k_pass2(const float* __restrict__ gt,
                                               const float* __restrict__ priors,
                                               const u64* __restrict__ bk,
                                               const u8* __restrict__ bidx,
                                               const float* __restrict__ loc_preds,
                                               const float* __restrict__ scores,
                                               float* __restrict__ mine,
                                               double* __restrict__ pl,
                                               double* __restrict__ pc,
                                               int* __restrict__ pn) {
    const int b = blockIdx.y;
    const int tid = threadIdx.x;
    const int wave = tid >> 6, lane = tid & 63;
    __shared__ float s_slab[4][2][SLABF];   // 4 waves x 2 bufs x padded slab
    __shared__ float s_gt[O * 5];
    __shared__ int s_bp[O];

    if (tid < O * 5) s_gt[tid] = gt[b * O * 5 + tid];
    if (tid < O) {
        u64 k = bk[((size_t)b * O + tid) * NB1];
#pragma unroll
        for (int i = 1; i < NB1; i++) {
            u64 v = bk[((size_t)b * O + tid) * NB1 + i];
            k = (v > k) ? v : k;
        }
        s_bp[tid] = (int)(0xFFFFFFFFu - (u32)(k & 0xFFFFFFFFull));
    }
    __syncthreads();

    const int wbase = blockIdx.x * BPB + wave * WPW;
    int wp = P - wbase; if (wp > WPW) wp = WPW;
    const int nchunk = (wp > 0) ? ((wp + 63) >> 6) : 0;

    double l_loc = 0.0, l_ce = 0.0;
    int l_np = 0;

    if (nchunk > 0) {
        {
            int nv0 = wp < 64 ? wp : 64;
            stage64(scores + ((size_t)b * P + wbase) * NC,
                    &s_slab[wave][0][0], nv0 * 21 / 4, lane);
        }
        for (int c = 0; c < nchunk; ++c) {
            const int base = wbase + c * 64;
            int nv = wp - c * 64; if (nv > 64) nv = 64;

            if (c + 1 < nchunk) {
                int nv2 = wp - (c + 1) * 64; if (nv2 > 64) nv2 = 64;
                asm volatile("s_waitcnt lgkmcnt(0)" ::: "memory");  // drain reads of buf being overwritten
                stage64(scores + ((size_t)b * P + base + 64) * NC,
                        &s_slab[wave][(c + 1) & 1][0], nv2 * 21 / 4, lane);
                asm volatile("s_waitcnt vmcnt(6)" ::: "memory");    // chunk c landed; c+1 stays in flight
            } else {
                asm volatile("s_waitcnt vmcnt(0)" ::: "memory");
            }
            __builtin_amdgcn_sched_barrier(0);

            if (lane < nv) {
                const int p = base + lane;
                const float* fsl = &s_slab[wave][c & 1][lane * NC];
                float fs[NC];
#pragma unroll
                for (int cc = 0; cc < NC; cc++) fs[cc] = fsl[cc];   // stride-21: 2-way bank = free

                int e = (int)bidx[(size_t)b * P + p];
                int best_idx = e & 0x3F;
                bool matched = (e & 0x80) != 0;
#pragma unroll
                for (int o = 0; o < O; o++) {
                    if (s_bp[o] == p) { best_idx = o; matched = true; }   // last wins
                }
                int cls = matched ? (int)s_gt[best_idx * 5 + 4] : 0;

                float mx = fs[0];
#pragma unroll
                for (int cc = 1; cc < NC; cc++) mx = fmaxf(mx, fs[cc]);
                float se = 0.0f;
#pragma unroll
                for (int cc = 0; cc < NC; cc++) se += __expf(fs[cc] - mx);
                float lse = mx + __logf(se);
                float g = fs[0];
#pragma unroll
                for (int cc = 1; cc < NC; cc++) g = (cc == cls) ? fs[cc] : g;
                float ce = lse - g;

                bool pos = cls > 0;
                mine[(size_t)b * P + p] = pos ? 0.0f : ce;

                if (pos) {
                    l_np++;
                    l_ce += (double)ce;
                    float4 pr = reinterpret_cast<const float4*>(priors)[p];
                    float m0 = s_gt[best_idx * 5 + 0], m1 = s_gt[best_idx * 5 + 1];
                    float m2 = s_gt[best_idx * 5 + 2], m3 = s_gt[best_idx * 5 + 3];
                    float tx = ((m0 + m2) * 0.5f - pr.x) / (0.1f * pr.z);
                    float ty = ((m1 + m3) * 0.5f - pr.y) / (0.1f * pr.w);
                    float tw = __logf((m2 - m0) / pr.z) * 5.0f;
                    float th = __logf((m3 - m1) / pr.w) * 5.0f;
                    float4 lp = reinterpret_cast<const float4*>(loc_preds)[(size_t)b * P + p];
                    float d0 = fabsf(lp.x - tx), d1 = fabsf(lp.y - ty);
                    float d2 = fabsf(lp.z - tw), d3 = fabsf(lp.w - th);
                    float s0 = d0 < 1.0f ? 0.5f * d0 * d0 : d0 - 0.5f;
                    float s1 = d1 < 1.0f ? 0.5f * d1 * d1 : d1 - 0.5f;
                    float s2 = d2 < 1.0f ? 0.5f * d2 * d2 : d2 - 0.5f;
                    float s3 = d3 < 1.0f ? 0.5f * d3 * d3 : d3 - 0.5f;
                    l_loc += (double)((s0 + s1) + (s2 + s3));
                }
            }
        }
    }

    // wave shuffle reductions -> plain partial stores
#pragma unroll
    for (int off = 32; off > 0; off >>= 1) {
        l_loc += __shfl_xor(l_loc, off, 64);
        l_ce  += __shfl_xor(l_ce, off, 64);
        l_np  += __shfl_xor(l_np, off, 64);
    }
    __shared__ double s_loc[4], s_ce[4];
    __shared__ int s_np[4];
    if (lane == 0) { s_loc[wave] = l_loc; s_ce[wave] = l_ce; s_np[wave] = l_np; }
    __syncthreads();
    if (tid == 0) {
        int q = b * NBX2 + blockIdx.x;
        pl[q] = (s_loc[0] + s_loc[1]) + (s_loc[2] + s_loc[3]);
        pc[q] = (s_ce[0] + s_ce[1]) + (s_ce[2] + s_ce[3]);
        pn[q] = s_np[0] + s_np[1] + s_np[2] + s_np[3];
    }
}

// Hard-negative top-k sum; self-computes total_pos; plain stores; no atomics.
__global__ void __launch_bounds__(1024) k_hardneg(const float* __restrict__ mine,
                                                  const int* __restrict__ pn,
                                                  double* __restrict__ pneg) {
    const int b = blockIdx.x;
    const int tid = threadIdx.x;
    const int lane = tid & 63, wave = tid >> 6;
    __shared__ float s_mine[P];
    __shared__ u32 s_hist[256];
    __shared__ u32 s_sel[2];
    __shared__ double s_red[16];
    __shared__ int s_ti[16];
    __shared__ int s_npx[NBX2];
    __shared__ int s_k;

    {
        int t = 0;
        for (int i = tid; i < NPART; i += 1024) t += pn[i];
#pragma unroll
        for (int off = 32; off > 0; off >>= 1) t += __shfl_xor(t, off, 64);
        if (lane == 0) s_ti[wave] = t;
    }
    if (tid < NBX2) s_npx[tid] = pn[b * NBX2 + tid];
    __syncthreads();
    if (tid == 0) {
        int tp = 0;
#pragma unroll
        for (int w = 0; w < 16; w++) tp += s_ti[w];
        int np = 0;
#pragma unroll
        for (int x = 0; x < NBX2; x++) np += s_npx[x];
        int k = 3 * np;
        int cap = P - tp - 1;
        if (cap < k) k = cap;
        s_k = k;
    }
    __syncthreads();
    const int k = s_k;

    if (k <= 0) {
        if (tid == 0) pneg[b] = 0.0;
        return;
    }

    for (int i = tid; i < P; i += 1024) s_mine[i] = mine[(size_t)b * P + i];
    if (tid == 0) { s_sel[0] = 0u; s_sel[1] = (u32)k; }
    __syncthreads();

    for (int shift = 24; shift >= 0; shift -= 8) {
        if (tid < 256) s_hist[tid] = 0u;
        __syncthreads();
        u32 prefix = s_sel[0];
        u32 kr = s_sel[1];
        u32 himask = (shift == 24) ? 0u : (0xFFFFFFFFu << (shift + 8));
        for (int i = tid; i < P; i += 1024) {
            u32 v = __float_as_uint(s_mine[i]);
            if ((v & himask) == prefix) atomicAdd(&s_hist[(v >> shift) & 255u], 1u);
        }
        __syncthreads();
        if (tid < 64) {
            const int L = tid;
            const int btop = 255 - 4 * L;
            u32 h0 = s_hist[btop], h1 = s_hist[btop - 1], h2 = s_hist[btop - 2], h3 = s_hist[btop - 3];
            u32 g4 = h0 + h1 + h2 + h3;
            u32 x = g4;
#pragma unroll
            for (int off = 1; off < 64; off <<= 1) {
                u32 v = __shfl_up(x, off, 64);
                if (L >= off) x += v;
            }
            u32 excl = x - g4;
            if (excl < kr && excl + g4 >= kr) {
                u32 c = excl; int chosen = btop; u32 kloc = kr;
                u32 nc;
                nc = c + h0; if (c < kr && nc >= kr) { chosen = btop;     kloc = kr - c; } c = nc;
                nc = c + h1; if (c < kr && nc >= kr) { chosen = btop - 1; kloc = kr - c; } c = nc;
                nc = c + h2; if (c < kr && nc >= kr) { chosen = btop - 2; kloc = kr - c; } c = nc;
                nc = c + h3; if (c < kr && nc >= kr) { chosen = btop - 3; kloc = kr - c; } c = nc;
                s_sel[0] = prefix | ((u32)chosen << shift);
                s_sel[1] = kloc;
            }
        }
        __syncthreads();
    }

    u32 tbits = s_sel[0];
    u32 kr = s_sel[1];
    float T = __uint_as_float(tbits);

    double sd = 0.0;
    for (int i = tid; i < P; i += 1024) {
        u32 v = __float_as_uint(s_mine[i]);
        if (v > tbits) sd += (double)s_mine[i];
    }
#pragma unroll
    for (int off = 32; off > 0; off >>= 1) sd += __shfl_xor(sd, off, 64);
    if (lane == 0) s_red[wave] = sd;
    __syncthreads();
    if (tid == 0) {
        double tt = 0.0;
#pragma unroll
        for (int w = 0; w < 16; w++) tt += s_red[w];
        pneg[b] = tt + (double)kr * (double)T;
    }
}

// Final: sum all partials, write both outputs.
__global__ void __launch_bounds__(1024) k_fin(const double* __restrict__ pl,
                                              const double* __restrict__ pc,
                                              const int* __restrict__ pn,
                                              const double* __restrict__ pneg,
                                              float* __restrict__ out) {
    const int tid = threadIdx.x;
    const int lane = tid & 63, wave = tid >> 6;
    __shared__ double s_l[16], s_c[16], s_g[16];
    __shared__ int s_t[16];

    double tl = 0.0, tc = 0.0, tg = 0.0;
    int tn = 0;
    for (int i = tid; i < NPART; i += 1024) { tl += pl[i]; tc += pc[i]; tn += pn[i]; }
    if (tid < B) tg = pneg[tid];
#pragma unroll
    for (int off = 32; off > 0; off >>= 1) {
        tl += __shfl_xor(tl, off, 64);
        tc += __shfl_xor(tc, off, 64);
        tg += __shfl_xor(tg, off, 64);
        tn += __shfl_xor(tn, off, 64);
    }
    if (lane == 0) { s_l[wave] = tl; s_c[wave] = tc; s_g[wave] = tg; s_t[wave] = tn; }
    __syncthreads();
    if (tid == 0) {
        double al = 0.0, ac = 0.0, ag = 0.0;
        int an = 0;
#pragma unroll
        for (int w = 0; w < 16; w++) { al += s_l[w]; ac += s_c[w]; ag += s_g[w]; an += s_t[w]; }
        double n = (double)an;
        out[0] = (float)(al / n);
        out[1] = (float)((ac + ag) / n);
    }
}

extern "C" void kernel_launch(void* const* d_in, const int* in_sizes, int n_in,
                              void* d_out, int out_size, void* d_ws, size_t ws_size,
                              hipStream_t stream) {
    const float* loc_preds = (const float*)d_in[0];
    const float* scores    = (const float*)d_in[1];
    const float* gt        = (const float*)d_in[2];
    const float* priors    = (const float*)d_in[3];

    char* ws = (char*)d_ws;
    u64* bk      = (u64*)ws;                  // [0, 131072)        B*O*NB1 u64
    double* pl   = (double*)(ws + 131072);    // [131072, 137216)   NPART dbl
    double* pc   = (double*)(ws + 137216);    // [137216, 143360)
    int* pn      = (int*)(ws + 143360);       // [143360, 146432)
    double* pneg = (double*)(ws + 146432);    // [146432, 147456)
    u8* bidx     = (u8*)(ws + 147456);        // [147456, 1265152)  B*P u8
    float* mine  = (float*)(ws + 1265152);    // B*P*4 (16B-aligned)

    // no memset needed: every ws slot consumed is plainly overwritten each call

    k_pass1<<<dim3(NB1, B), dim3(256), 0, stream>>>(gt, priors, bk, bidx);
    k_pass2<<<dim3(NBX2, B), dim3(256), 0, stream>>>(
        gt, priors, bk, bidx, loc_preds, scores, mine, pl, pc, pn);
    k_hardneg<<<dim3(B), dim3(1024), 0, stream>>>(mine, pn, pneg);
    k_fin<<<dim3(1), dim3(1024), 0, stream>>>(pl, pc, pn, pneg, (float*)d_out);
}